// Round 14
// baseline (174.258 us; speedup 1.0000x reference)
//
#include <hip/hip_runtime.h>
#include <hip/hip_bf16.h>

#define NMODELS 64
#define BBATCH  4096
#define IN_DIM  64
#define H_DIM   256

typedef __attribute__((ext_vector_type(8))) short short8;
typedef __attribute__((ext_vector_type(4))) float floatx4;
typedef __attribute__((ext_vector_type(4))) unsigned int uint4v;
typedef __attribute__((ext_vector_type(2))) unsigned int uint2v;

__device__ __forceinline__ unsigned short f2bf(float f) {   // prep only
    unsigned int u = __builtin_bit_cast(unsigned int, f);
    return (unsigned short)((u + 0x8000u) >> 16);
}
// packed fp32x2 -> bf16x2 (v_cvt_pk_bf16_f32 on gfx950), RNE
__device__ __forceinline__ unsigned int pkbf(float a, float b) {
    __hip_bfloat162 h = __float22bfloat162_rn(make_float2(a, b));
    unsigned int u;
    __builtin_memcpy(&u, &h, 4);
    return u;
}

// Transpose+cvt: W1 [M][64][256]->w1t [M][256][64] bf16 (blocks 0..255)
//                W2 [M][256][256]->w2t [M][256][256] bf16 (blocks 256..1279)
__global__ __launch_bounds__(256) void prep_weights(const float* __restrict__ W1,
                                                    const float* __restrict__ W2,
                                                    unsigned short* __restrict__ w1t,
                                                    unsigned short* __restrict__ w2t) {
    __shared__ float lds[64][65];
    const int bid = blockIdx.x;
    const float* src;
    unsigned short* dst;
    int K, N, m, kb, nb;
    if (bid < 256) {
        m = bid >> 2; kb = 0; nb = bid & 3; K = IN_DIM; N = H_DIM;
        src = W1; dst = w1t;
    } else {
        int t = bid - 256;
        m = t >> 4; kb = (t >> 2) & 3; nb = t & 3; K = H_DIM; N = H_DIM;
        src = W2; dst = w2t;
    }
    const float* s = src + ((size_t)m * K + (size_t)kb * 64) * N + nb * 64;
    const int tid = threadIdx.x;
    const int r = tid >> 4, c4 = (tid & 15) * 4;
#pragma unroll
    for (int p = 0; p < 4; ++p) {
        int row = p * 16 + r;                      // k-local 0..63
        float4 v = *(const float4*)(s + (size_t)row * N + c4);
        lds[row][c4] = v.x; lds[row][c4 + 1] = v.y;
        lds[row][c4 + 2] = v.z; lds[row][c4 + 3] = v.w;
    }
    __syncthreads();
    unsigned short* dbase = dst + ((size_t)m * N + (size_t)nb * 64) * K + kb * 64;
    const int j = tid & 7;                         // k-chunk 0..7
#pragma unroll
    for (int it = 0; it < 2; ++it) {
        int n = it * 32 + (tid >> 3);              // n-local 0..63
        unsigned short tmp[8];
#pragma unroll
        for (int e = 0; e < 8; ++e) tmp[e] = f2bf(lds[j * 8 + e][n]);
        *(short8*)(dbase + (size_t)n * K + j * 8) = *(const short8*)tmp;
    }
}

// Fused 3-layer MLP, T=2 tiles/WG, 2 WG/CU (R12 champion, 82.6us) + same-
// model co-residency remap. Old swizzle: co-resident WGs on a CU were
// wl and wl+32 -> DIFFERENT models -> 2x128KB distinct W2 streams, zero L1
// sharing. New within-XCD map wg = x*256 + (wl&7)*32 + (wl>>3) (bijective,
// 3+5 bits): co-resident WGs are the SAME model, tiles 4 apart -> both WGs'
// waves read the identical W2 slice set -> WG-B's bw/bv ride WG-A's L1/L2
// lines; per-CU L2 demand halves. Extends R9's XCD-level locality win
// (101->84us) one cache level down. Model set per XCD unchanged (8 models).
// Ledger: structural variants all worse (T=1 131, row-split 167, T=2-seq
// 131, persistent 186-207 spill, rotation 86.5); champion micro-opts
// 101->84 (XCD swizzle) ->82.6 (scatter/gather tail).
__global__ __launch_bounds__(256, 2) void mlp_fused(
    const float* __restrict__ xs,
    const unsigned short* __restrict__ w1t,   // [M][H][IN] bf16
    const float* __restrict__ b1,
    const unsigned short* __restrict__ w2t,   // [M][H][H] bf16 (n-major)
    const float* __restrict__ b2,
    const float* __restrict__ w3,             // [M][H]
    const float* __restrict__ b3,             // [M]
    float* __restrict__ out)                  // [M][B]
{
    __shared__ unsigned short h1s[2][64 * 256];   // 64 KB; phase-3 pslab overlay

    const int bid = blockIdx.x;
    const int x   = bid & 7;                      // XCD (bid % 8)
    const int wl  = bid >> 3;                     // within-XCD index 0..255
    const int wg  = x * 256 + (wl & 7) * 32 + (wl >> 3);
    const int m     = wg >> 5;                    // 8 models per XCD
    const int tile0 = (wg & 31) * 2;              // this WG: tiles tile0, tile0+1
    const int tid = threadIdx.x;
    const int w   = tid >> 6;
    const int lane = tid & 63;
    const int q   = lane >> 4;
    const int c16 = lane & 15;
    const int sw  = c16 & 7;

    // b1 needed in phase-1 epilogue; hoist only it (b2/w3/b3 sunk below)
    floatx4 b1v = *(const floatx4*)(b1 + m * H_DIM + w * 64 + c16 * 4);

    // ---------------- Phase 1: h1[t] = relu(x[t] @ W1 + b1), t=0,1 ----------------
    const float* xrow0 = xs + ((size_t)m * BBATCH + (size_t)tile0 * 64) * IN_DIM;
    const unsigned short* w1p = w1t + (size_t)m * (H_DIM * IN_DIM)
                                + (w * 64 + c16 * 4) * IN_DIM + q * 8;
    const unsigned short* w2p = w2t + (size_t)m * (H_DIM * H_DIM)
                                + (w * 64 + c16 * 4) * H_DIM + q * 8;

    short8 ax[2][4][2];
#pragma unroll
    for (int t = 0; t < 2; ++t)
#pragma unroll
        for (int rb = 0; rb < 4; ++rb)
#pragma unroll
            for (int kb = 0; kb < 2; ++kb) {
                const float* xp = xrow0 + (size_t)t * 64 * IN_DIM
                                  + (rb * 16 + c16) * IN_DIM + kb * 32 + q * 8;
                float4 v0 = *(const float4*)xp;
                float4 v1 = *(const float4*)(xp + 4);
                uint4v u;
                u[0] = pkbf(v0.x, v0.y); u[1] = pkbf(v0.z, v0.w);
                u[2] = pkbf(v1.x, v1.y); u[3] = pkbf(v1.z, v1.w);
                ax[t][rb][kb] = __builtin_bit_cast(short8, u);
            }

    floatx4 acc[2][4][4];
#pragma unroll
    for (int t = 0; t < 2; ++t)
#pragma unroll
        for (int rb = 0; rb < 4; ++rb)
#pragma unroll
            for (int nb = 0; nb < 4; ++nb)
                acc[t][rb][nb] = (floatx4){0.f, 0.f, 0.f, 0.f};

    {
        short8 bw[2][4];                          // shared across both tiles
#pragma unroll
        for (int kb = 0; kb < 2; ++kb)
#pragma unroll
            for (int nb = 0; nb < 4; ++nb)
                bw[kb][nb] = *(const short8*)(w1p + nb * IN_DIM + kb * 32);
        __builtin_amdgcn_s_setprio(1);
#pragma unroll
        for (int t = 0; t < 2; ++t)
#pragma unroll
            for (int kb = 0; kb < 2; ++kb)
#pragma unroll
                for (int nb = 0; nb < 4; ++nb)
#pragma unroll
                    for (int rb = 0; rb < 4; ++rb)
                        acc[t][rb][nb] = __builtin_amdgcn_mfma_f32_16x16x32_bf16(
                            ax[t][rb][kb], bw[kb][nb], acc[t][rb][nb], 0, 0, 0);
        __builtin_amdgcn_s_setprio(0);
    }

    // Prefetch phase-2 B slots kb=0,1 (h1-independent): L2 latency overlaps
    // the epilogue cvt/ds_write and the barrier drain.
    short8 bv[3][4];
#pragma unroll
    for (int nb = 0; nb < 4; ++nb) bv[0][nb] = *(const short8*)(w2p + nb * H_DIM + 0 * 32);
#pragma unroll
    for (int nb = 0; nb < 4; ++nb) bv[1][nb] = *(const short8*)(w2p + nb * H_DIM + 1 * 32);

    // phase-3-only uniform loads: issue here so latency hides under epilogue
    // + barrier + phase 2 (consumed only after phase 2).
    floatx4 b2v = *(const floatx4*)(b2 + m * H_DIM + w * 64 + c16 * 4);
    floatx4 w3v = *(const floatx4*)(w3 + m * H_DIM + w * 64 + c16 * 4);
    const float b3v = b3[m];

    {   // epilogue: bias+relu+packed cvt, 8B ds_write per (t,rb,r), 16B-chunk XOR swizzle
#pragma unroll
        for (int t = 0; t < 2; ++t)
#pragma unroll
            for (int rb = 0; rb < 4; ++rb)
#pragma unroll
                for (int r = 0; r < 4; ++r) {
                    float v0 = fmaxf(acc[t][rb][0][r] + b1v[0], 0.f);
                    float v1 = fmaxf(acc[t][rb][1][r] + b1v[1], 0.f);
                    float v2 = fmaxf(acc[t][rb][2][r] + b1v[2], 0.f);
                    float v3 = fmaxf(acc[t][rb][3][r] + b1v[3], 0.f);
                    uint2v u2; u2[0] = pkbf(v0, v1); u2[1] = pkbf(v2, v3);
                    int row = rb * 16 + q * 4 + r;
                    int chunk = (w * 8 + (c16 >> 1)) ^ (row & 7);
                    *(uint2v*)((char*)&h1s[t][0] + row * 512 + chunk * 16 + (c16 & 1) * 8) = u2;
                }
    }
    __syncthreads();

    // ---------------- Phase 2: h2[t] = relu(h1[t] @ W2 + b2); pipelined B ----------
#pragma unroll
    for (int t = 0; t < 2; ++t)
#pragma unroll
        for (int rb = 0; rb < 4; ++rb)
#pragma unroll
            for (int nb = 0; nb < 4; ++nb)
                acc[t][rb][nb] = (floatx4){0.f, 0.f, 0.f, 0.f};

#pragma unroll
    for (int kb = 0; kb < 8; ++kb) {
        const int cur = kb % 3;
        const int pre = (kb + 2) % 3;
        if (kb < 6) {                             // keep depth-2 in flight
#pragma unroll
            for (int nb = 0; nb < 4; ++nb)
                bv[pre][nb] = *(const short8*)(w2p + nb * H_DIM + (kb + 2) * 32);
        }
        short8 av[2][4];
#pragma unroll
        for (int t = 0; t < 2; ++t)
#pragma unroll
            for (int rb = 0; rb < 4; ++rb)
                av[t][rb] = *(const short8*)((char*)&h1s[t][0] + (rb * 16 + c16) * 512
                                             + (((kb * 4 + q) ^ sw) * 16));
        __builtin_amdgcn_s_setprio(1);
#pragma unroll
        for (int nb = 0; nb < 4; ++nb)
#pragma unroll
            for (int t = 0; t < 2; ++t)
#pragma unroll
                for (int rb = 0; rb < 4; ++rb)
                    acc[t][rb][nb] = __builtin_amdgcn_mfma_f32_16x16x32_bf16(
                        av[t][rb], bv[cur][nb], acc[t][rb][nb], 0, 0, 0);
        __builtin_amdgcn_s_setprio(0);
    }

    // ---------------- Phase 3: out = h2 @ W3 + b3 (OUT=1) ----------------------
    // Fold (VALU only, no LDS — overlaps other waves' phase-2 tails)
    float p[2][4][4];
#pragma unroll
    for (int t = 0; t < 2; ++t)
#pragma unroll
        for (int rb = 0; rb < 4; ++rb)
#pragma unroll
            for (int r = 0; r < 4; ++r) p[t][rb][r] = 0.f;
#pragma unroll
    for (int t = 0; t < 2; ++t)
#pragma unroll
        for (int rb = 0; rb < 4; ++rb)
#pragma unroll
            for (int nb = 0; nb < 4; ++nb)
#pragma unroll
                for (int r = 0; r < 4; ++r) {
                    float v = fmaxf(acc[t][rb][nb][r] + b2v[nb], 0.f);
                    p[t][rb][r] += v * w3v[nb];
                }

    __syncthreads();   // all h1 reads done -> overlay pslab on h1s

    // Scatter: thread tid owns a 32-float (128 B) region; 8 x ds_write_b128
    // at chunk (t*4+rb) ^ (tid&7) -> b128 bank-floor (each 8-lane group
    // covers all 32 banks).
    {
        float* myreg = (float*)&h1s[0][0] + tid * 32;
#pragma unroll
        for (int t = 0; t < 2; ++t)
#pragma unroll
            for (int rb = 0; rb < 4; ++rb) {
                int c = t * 4 + rb;
                float4 v4 = make_float4(p[t][rb][0], p[t][rb][1],
                                        p[t][rb][2], p[t][rb][3]);
                *(float4*)(myreg + (((c ^ (tid & 7)) << 2))) = v4;
            }
    }
    __syncthreads();

    // Gather: 128 threads, one output row each. Row (t, rb,q0,r) sums 64
    // sources: threads {w4*64 + q0*16 + cc}, value v = t*16+rb*4+r at
    // chunk (v>>2) ^ (src&7), word v&3. src&7 == cc&7 (q0*16 ≡ 0 mod 8).
    if (tid < 128) {
        const int t  = tid >> 6, row = tid & 63;
        const int rb = row >> 4, q0 = (row >> 2) & 3, r = row & 3;
        const int v  = t * 16 + rb * 4 + r;
        const int c  = v >> 2, j = v & 3;
        const float* pslab = (const float*)&h1s[0][0];
        float sacc[4] = {0.f, 0.f, 0.f, 0.f};
#pragma unroll
        for (int w4 = 0; w4 < 4; ++w4)
#pragma unroll
            for (int cc = 0; cc < 16; ++cc) {
                int src = w4 * 64 + q0 * 16 + cc;
                sacc[w4] += pslab[src * 32 + ((c ^ (cc & 7)) << 2) + j];
            }
        float s = (sacc[0] + sacc[1]) + (sacc[2] + sacc[3]) + b3v;
        out[(size_t)m * BBATCH + (size_t)(tile0 + t) * 64 + row] = s;
    }
}

extern "C" void kernel_launch(void* const* d_in, const int* in_sizes, int n_in,
                              void* d_out, int out_size, void* d_ws, size_t ws_size,
                              hipStream_t stream) {
    const float* xs = (const float*)d_in[0];
    const float* W1 = (const float*)d_in[1];
    const float* b1 = (const float*)d_in[2];
    const float* W2 = (const float*)d_in[3];
    const float* b2 = (const float*)d_in[4];
    const float* W3 = (const float*)d_in[5];
    const float* b3 = (const float*)d_in[6];
    float* out = (float*)d_out;

    unsigned short* w1t = (unsigned short*)d_ws;                    // 2 MB
    unsigned short* w2t = w1t + (size_t)NMODELS * H_DIM * IN_DIM;   // 8.4 MB

    prep_weights<<<256 + NMODELS * 16, 256, 0, stream>>>(W1, W2, w1t, w2t);
    mlp_fused<<<NMODELS * (BBATCH / 128), 256, 0, stream>>>(xs, w1t, b1, w2t, b2, W3, b3, out);
}